// Round 9
// baseline (110.801 us; speedup 1.0000x reference)
//
#include <hip/hip_runtime.h>
#include <hip/hip_bf16.h>

typedef float f32x4 __attribute__((ext_vector_type(4)));

#define NB 32      // batch
#define NT 2000    // time
#define NW 512     // width
#define NG 20      // groups (T / NUM_STEPS)
#define NS 100     // NUM_STEPS
#define NH 1024    // hidden
#define NO 10      // outputs
#define BETA 0.95f
#define THRESH 1.0f

// ------- Kernel 1 (fused): conv+scan1 blocks [0,1280) + transpose blocks [1280,1792) -------
// k1 part: ROUND-3 VERSION, marginal-measured ~78us (round 5) = HBM roofline. FROZEN.
// transpose rides along (8 MB vs 524 MB) -> saves one dispatch + launch gap.
__global__ __launch_bounds__(256) void k1_conv_scan_tr(
    const f32x4* __restrict__ x,    // [B][T][W] of float4 (C=4 innermost)
    const float* __restrict__ cw,   // [4]
    const float* __restrict__ cb,   // [1]
    float* __restrict__ spk1,       // [B][G][W]
    const float* __restrict__ wsrc, // [H][W] hidden_w
    float* __restrict__ wT)         // [W][H]
{
    __shared__ float tile[32][33];
    int bid = blockIdx.x;

    if (bid < 1280) {
        int half = bid & 1;             // which half of the 512-wide row
        int bg = bid >> 1;              // 0..639
        int g = bg % NG;
        int b = bg / NG;
        int tid = threadIdx.x;          // 0..255

        const f32x4* __restrict__ base =
            x + ((size_t)(b * NT + g * NS) * NW + half * 256);

        float w0 = cw[0], w1 = cw[1], w2 = cw[2], w3 = cw[3];
        float bias = cb[0];

        f32x4 A[10], B[10];
        float mem = 0.0f;

#define LOAD10(dst, S0)                                                        \
    {                                                                          \
        _Pragma("unroll")                                                      \
        for (int j = 0; j < 10; ++j)                                           \
            dst[j] = __builtin_nontemporal_load(base + (tid + ((S0) + j) * NW)); \
    }
#define STEP10(src)                                                            \
    {                                                                          \
        _Pragma("unroll")                                                      \
        for (int j = 0; j < 10; ++j) {                                         \
            f32x4 v = src[j];                                                  \
            float f = fmaf(v[0], w0, fmaf(v[1], w1,                            \
                      fmaf(v[2], w2, fmaf(v[3], w3, bias))));                  \
            float base_m = fmaf(BETA, mem, f);                                 \
            mem = (mem > THRESH) ? 0.0f : base_m;                              \
        }                                                                      \
    }

        LOAD10(A, 0)
        LOAD10(B, 10) STEP10(A)
        LOAD10(A, 20) STEP10(B)
        LOAD10(B, 30) STEP10(A)
        LOAD10(A, 40) STEP10(B)
        LOAD10(B, 50) STEP10(A)
        LOAD10(A, 60) STEP10(B)
        LOAD10(B, 70) STEP10(A)
        LOAD10(A, 80) STEP10(B)
        LOAD10(B, 90) STEP10(A)
        STEP10(B)
#undef LOAD10
#undef STEP10

        spk1[(b * NG + g) * NW + half * 256 + tid] = (mem > THRESH) ? 1.0f : 0.0f;
    } else {
        // transpose hidden_w (1024x512 -> 512x1024)
        int tbid = bid - 1280;           // 0..511
        int bk = tbid & 15;              // 16 tiles over W
        int bh = tbid >> 4;              // 32 tiles over H
        int tx = threadIdx.x & 31;       // 0..31
        int ty = threadIdx.x >> 5;       // 0..7
        #pragma unroll
        for (int j = 0; j < 4; ++j)
            tile[ty + j * 8][tx] = wsrc[(bh * 32 + ty + j * 8) * NW + bk * 32 + tx];
        __syncthreads();
        #pragma unroll
        for (int j = 0; j < 4; ++j)
            wT[(bk * 32 + ty + j * 8) * NH + bh * 32 + tx] = tile[tx][ty + j * 8];
    }
}

// ---------------- Kernel 2 v4: hidden GEMM + 20-step scan ----------------------
// Round-8 arithmetic: total broadcast ds_reads = 1.31M / h_per_thread; v3's
// h_pt=2 put ~10.7us on the LDS pipe. v4: h-QUAD per thread (h_pt=4) halves
// LDS work; 8 k-chunks of 64 via c=t>>5 (half-wave-uniform sk reads = free
// 2-way broadcast); float4 wT loads stay coalesced (512B per 32 lanes).
// 256 blocks = 1/CU. Reduction: two-phase RMW (c>=4 adds into c-4), g in two
// rounds of 10 through red[4][10][32] (20KB; 60KB static total, as v3).
__global__ __launch_bounds__(256) void k2_hidden_scan(
    const float* __restrict__ spk1,  // [B][G][W]
    const float* __restrict__ wT,    // [W][H]
    const float* __restrict__ hb,    // [H]
    float* __restrict__ spk2)        // [B][H]
{
    __shared__ float sk[NG][NW];     // 40 KB: spk1[b] slice
    __shared__ f32x4 red[4][10][32]; // 20 KB: reduction buffer (g-halves)

    int bid = blockIdx.x;            // 0..255
    int b = bid >> 3;                // 0..31
    int hgrp = bid & 7;              // 0..7 (128 h per block)
    int t = threadIdx.x;
    int lane5 = t & 31;
    int c = t >> 5;                  // k-chunk 0..7 (64 kk each)
    int h = hgrp * 128 + lane5 * 4;  // h-quad base

    // cooperative stage: 2560 float4 / 256 threads = 10 each, coalesced
    {
        const f32x4* __restrict__ sp4 =
            (const f32x4*)(spk1 + (size_t)b * NG * NW);
        f32x4* sk4 = (f32x4*)&sk[0][0];
        #pragma unroll
        for (int i = 0; i < 10; ++i)
            sk4[t + i * 256] = sp4[t + i * 256];
    }
    __syncthreads();

    f32x4 acc[NG];
    #pragma unroll
    for (int g = 0; g < NG; ++g)
        #pragma unroll
        for (int j = 0; j < 4; ++j) acc[g][j] = 0.0f;

    int k0 = c * 64;
    #pragma unroll 2
    for (int kkg = 0; kkg < 16; ++kkg) {
        int kk = k0 + kkg * 4;
        f32x4 w0 = *(const f32x4*)&wT[(kk + 0) * NH + h];
        f32x4 w1 = *(const f32x4*)&wT[(kk + 1) * NH + h];
        f32x4 w2 = *(const f32x4*)&wT[(kk + 2) * NH + h];
        f32x4 w3 = *(const f32x4*)&wT[(kk + 3) * NH + h];
        #pragma unroll
        for (int g = 0; g < NG; ++g) {
            f32x4 u = *(const f32x4*)&sk[g][kk];   // half-wave-uniform broadcast
            #pragma unroll
            for (int j = 0; j < 4; ++j)
                acc[g][j] = fmaf(u[0], w0[j], fmaf(u[1], w1[j],
                            fmaf(u[2], w2[j], fmaf(u[3], w3[j], acc[g][j]))));
        }
    }

    // scan state (threads t<128 each own one h)
    float hbias = 0.0f, mem = 0.0f;
    if (t < 128) hbias = hb[hgrp * 128 + t];
    int hl4 = t >> 2, hj = t & 3;

    #pragma unroll
    for (int half = 0; half < 2; ++half) {
        __syncthreads();
        if (c < 4) {
            #pragma unroll
            for (int gg = 0; gg < 10; ++gg)
                red[c][gg][lane5] = acc[half * 10 + gg];
        }
        __syncthreads();
        if (c >= 4) {
            #pragma unroll
            for (int gg = 0; gg < 10; ++gg) {
                f32x4 v = red[c - 4][gg][lane5];
                f32x4 a = acc[half * 10 + gg];
                #pragma unroll
                for (int j = 0; j < 4; ++j) v[j] += a[j];
                red[c - 4][gg][lane5] = v;
            }
        }
        __syncthreads();
        if (t < 128) {
            #pragma unroll
            for (int gg = 0; gg < 10; ++gg) {
                float xin = red[0][gg][hl4][hj] + red[1][gg][hl4][hj]
                          + red[2][gg][hl4][hj] + red[3][gg][hl4][hj] + hbias;
                float base = fmaf(BETA, mem, xin);
                mem = (mem > THRESH) ? 0.0f : base;
            }
        }
    }

    if (t < 128)
        spk2[b * NH + hgrp * 128 + t] = (mem > THRESH) ? 1.0f : 0.0f;
}

// ---------------- Kernel 3: output layer + softmax ----------------
__global__ __launch_bounds__(256) void k3_out(
    const float* __restrict__ spk2,  // [B][H]
    const float* __restrict__ ow,    // [O][H]
    const float* __restrict__ ob,    // [O]
    float* __restrict__ out)         // [B][O]
{
    int b = blockIdx.x;
    int t = threadIdx.x;

    float p[NO];
    #pragma unroll
    for (int o = 0; o < NO; ++o) p[o] = 0.0f;

    for (int h = t; h < NH; h += 256) {
        float s = spk2[b * NH + h];
        #pragma unroll
        for (int o = 0; o < NO; ++o) p[o] += s * ow[o * NH + h];
    }

    __shared__ float red[NO][256];
    #pragma unroll
    for (int o = 0; o < NO; ++o) red[o][t] = p[o];
    __syncthreads();

    for (int off = 128; off > 0; off >>= 1) {
        if (t < off) {
            #pragma unroll
            for (int o = 0; o < NO; ++o) red[o][t] += red[o][t + off];
        }
        __syncthreads();
    }

    if (t == 0) {
        float v[NO], mx = -1e30f;
        #pragma unroll
        for (int o = 0; o < NO; ++o) { v[o] = red[o][0] + ob[o]; mx = fmaxf(mx, v[o]); }
        float sum = 0.0f;
        #pragma unroll
        for (int o = 0; o < NO; ++o) { v[o] = expf(v[o] - mx); sum += v[o]; }
        float inv = 1.0f / sum;
        #pragma unroll
        for (int o = 0; o < NO; ++o) out[b * NO + o] = v[o] * inv;
    }
}

extern "C" void kernel_launch(void* const* d_in, const int* in_sizes, int n_in,
                              void* d_out, int out_size, void* d_ws, size_t ws_size,
                              hipStream_t stream) {
    const f32x4*  x  = (const f32x4*)d_in[0];   // [32][2000][512][4]
    const float*  cw = (const float*)d_in[1];   // [4]
    const float*  cb = (const float*)d_in[2];   // [1]
    const float*  hw = (const float*)d_in[3];   // [1024][512]
    const float*  hb = (const float*)d_in[4];   // [1024]
    const float*  ow = (const float*)d_in[5];   // [10][1024]
    const float*  ob = (const float*)d_in[6];   // [10]
    float* out = (float*)d_out;                 // [32][10]

    char* ws = (char*)d_ws;
    float* spk1 = (float*)(ws);                           // 32*20*512*4   = 1,310,720 B
    float* wT   = (float*)(ws + 1310720);                 // 512*1024*4    = 2,097,152 B
    float* spk2 = (float*)(ws + 1310720 + 2097152);       // 32*1024*4     =   131,072 B

    // stage 1: conv + scan1 (~78us, HBM roofline) fused with weight transpose
    k1_conv_scan_tr<<<1792, 256, 0, stream>>>(x, cw, cb, spk1, hw, wT);

    // stage 2+3: hidden GEMM (h-quad, 8 k-chunks, LDS-staged spk1) + scan2
    k2_hidden_scan<<<NB * 8, 256, 0, stream>>>(spk1, wT, hb, spk2);

    // stage 4: output + softmax
    k3_out<<<NB, 256, 0, stream>>>(spk2, ow, ob, out);
}

// Round 10
// 103.562 us; speedup vs baseline: 1.0699x; 1.0699x over previous
//
#include <hip/hip_runtime.h>
#include <hip/hip_bf16.h>

typedef float f32x4 __attribute__((ext_vector_type(4)));

#define NB 32      // batch
#define NT 2000    // time
#define NW 512     // width
#define NG 20      // groups (T / NUM_STEPS)
#define NS 100     // NUM_STEPS
#define NH 1024    // hidden
#define NO 10      // outputs
#define BETA 0.95f
#define THRESH 1.0f

// ------- Kernel 1 (fused): conv+scan1 blocks [0,1280) + transpose blocks [1280,1792) -------
// k1 part: ROUND-3 VERSION, marginal-measured ~78us (round 5) = HBM roofline. FROZEN.
__global__ __launch_bounds__(256) void k1_conv_scan_tr(
    const f32x4* __restrict__ x,    // [B][T][W] of float4 (C=4 innermost)
    const float* __restrict__ cw,   // [4]
    const float* __restrict__ cb,   // [1]
    float* __restrict__ spk1,       // [B][G][W]
    const float* __restrict__ wsrc, // [H][W] hidden_w
    float* __restrict__ wT)         // [W][H]
{
    __shared__ float tile[32][33];
    int bid = blockIdx.x;

    if (bid < 1280) {
        int half = bid & 1;             // which half of the 512-wide row
        int bg = bid >> 1;              // 0..639
        int g = bg % NG;
        int b = bg / NG;
        int tid = threadIdx.x;          // 0..255

        const f32x4* __restrict__ base =
            x + ((size_t)(b * NT + g * NS) * NW + half * 256);

        float w0 = cw[0], w1 = cw[1], w2 = cw[2], w3 = cw[3];
        float bias = cb[0];

        f32x4 A[10], B[10];
        float mem = 0.0f;

#define LOAD10(dst, S0)                                                        \
    {                                                                          \
        _Pragma("unroll")                                                      \
        for (int j = 0; j < 10; ++j)                                           \
            dst[j] = __builtin_nontemporal_load(base + (tid + ((S0) + j) * NW)); \
    }
#define STEP10(src)                                                            \
    {                                                                          \
        _Pragma("unroll")                                                      \
        for (int j = 0; j < 10; ++j) {                                         \
            f32x4 v = src[j];                                                  \
            float f = fmaf(v[0], w0, fmaf(v[1], w1,                            \
                      fmaf(v[2], w2, fmaf(v[3], w3, bias))));                  \
            float base_m = fmaf(BETA, mem, f);                                 \
            mem = (mem > THRESH) ? 0.0f : base_m;                              \
        }                                                                      \
    }

        LOAD10(A, 0)
        LOAD10(B, 10) STEP10(A)
        LOAD10(A, 20) STEP10(B)
        LOAD10(B, 30) STEP10(A)
        LOAD10(A, 40) STEP10(B)
        LOAD10(B, 50) STEP10(A)
        LOAD10(A, 60) STEP10(B)
        LOAD10(B, 70) STEP10(A)
        LOAD10(A, 80) STEP10(B)
        LOAD10(B, 90) STEP10(A)
        STEP10(B)
#undef LOAD10
#undef STEP10

        spk1[(b * NG + g) * NW + half * 256 + tid] = (mem > THRESH) ? 1.0f : 0.0f;
    } else {
        // transpose hidden_w (1024x512 -> 512x1024)
        int tbid = bid - 1280;           // 0..511
        int bk = tbid & 15;              // 16 tiles over W
        int bh = tbid >> 4;              // 32 tiles over H
        int tx = threadIdx.x & 31;       // 0..31
        int ty = threadIdx.x >> 5;       // 0..7
        #pragma unroll
        for (int j = 0; j < 4; ++j)
            tile[ty + j * 8][tx] = wsrc[(bh * 32 + ty + j * 8) * NW + bk * 32 + tx];
        __syncthreads();
        #pragma unroll
        for (int j = 0; j < 4; ++j)
            wT[(bk * 32 + ty + j * 8) * NH + bh * 32 + tx] = tile[tx][ty + j * 8];
    }
}

// ---------------- Kernel 2 v5: hidden GEMM + scan2 + output-partials ------------
// Round-9 null result falsified the LDS-throughput theory; k2 is LATENCY-bound
// at 1 wave/SIMD (grid was 1 block/CU). v5: 512 blocks (2 blocks/CU = 2
// waves/SIMD) of (b, 64-h group); float2 acc (40 VGPR, low pressure so many
// ds_read u's stay in flight); 8 k-chunks (c=t>>5, half-wave-uniform sk
// broadcasts). LDS 60 KB (sk 40 + red 20) -> exactly 2 blocks/CU.
// Epilogue folds the OUTPUT LAYER: wave 0 runs the 20-step scan (one h per
// lane), then 10 shfl-reduced dots against ow -> deterministic per-block
// partial[b][hgrp][o] (no atomics). spk2 buffer eliminated.
__global__ __launch_bounds__(256) void k2_hidden_scan(
    const float* __restrict__ spk1,  // [B][G][W]
    const float* __restrict__ wT,    // [W][H]
    const float* __restrict__ hb,    // [H]
    const float* __restrict__ ow,    // [O][H]
    float* __restrict__ partial)     // [B][16][10]
{
    __shared__ float sk[NG][NW];     // 40 KB: spk1[b] slice
    __shared__ float red[4][NG][64]; // 20 KB: reduction buffer

    int bid = blockIdx.x;            // 0..511
    int b = bid >> 4;                // 0..31
    int hgrp = bid & 15;             // 0..15 (64 h per block)
    int t = threadIdx.x;
    int lane5 = t & 31;
    int c = t >> 5;                  // k-chunk 0..7 (64 kk each)
    int h = hgrp * 64 + lane5 * 2;   // h-pair base

    // cooperative stage: 2560 float4 / 256 threads = 10 each, coalesced
    {
        const f32x4* __restrict__ sp4 =
            (const f32x4*)(spk1 + (size_t)b * NG * NW);
        f32x4* sk4 = (f32x4*)&sk[0][0];
        #pragma unroll
        for (int i = 0; i < 10; ++i)
            sk4[t + i * 256] = sp4[t + i * 256];
    }
    __syncthreads();

    float2 acc[NG];
    #pragma unroll
    for (int g = 0; g < NG; ++g) { acc[g].x = 0.0f; acc[g].y = 0.0f; }

    int k0 = c * 64;
    #pragma unroll 2
    for (int kkg = 0; kkg < 16; ++kkg) {
        int kk = k0 + kkg * 4;
        float2 a0 = *(const float2*)&wT[(kk + 0) * NH + h];
        float2 a1 = *(const float2*)&wT[(kk + 1) * NH + h];
        float2 a2 = *(const float2*)&wT[(kk + 2) * NH + h];
        float2 a3 = *(const float2*)&wT[(kk + 3) * NH + h];
        #pragma unroll
        for (int g = 0; g < NG; ++g) {
            f32x4 u = *(const f32x4*)&sk[g][kk];   // half-wave-uniform broadcast
            acc[g].x = fmaf(u[0], a0.x, fmaf(u[1], a1.x,
                       fmaf(u[2], a2.x, fmaf(u[3], a3.x, acc[g].x))));
            acc[g].y = fmaf(u[0], a0.y, fmaf(u[1], a1.y,
                       fmaf(u[2], a2.y, fmaf(u[3], a3.y, acc[g].y))));
        }
    }

    // two-phase reduction: chunks 0-3 write; chunks 4-7 accumulate in place
    if (c < 4) {
        #pragma unroll
        for (int g = 0; g < NG; ++g)
            *(float2*)&red[c][g][lane5 * 2] = acc[g];
    }
    __syncthreads();
    if (c >= 4) {
        #pragma unroll
        for (int g = 0; g < NG; ++g) {
            float2 v = *(float2*)&red[c - 4][g][lane5 * 2];
            v.x += acc[g].x; v.y += acc[g].y;
            *(float2*)&red[c - 4][g][lane5 * 2] = v;
        }
    }
    __syncthreads();

    // wave 0: 20-step scan (one h per lane) + folded output layer
    if (t < 64) {
        float hbias = hb[hgrp * 64 + t];
        float mem = 0.0f;
        #pragma unroll
        for (int g = 0; g < NG; ++g) {
            float xin = red[0][g][t] + red[1][g][t]
                      + red[2][g][t] + red[3][g][t] + hbias;
            float base = fmaf(BETA, mem, xin);
            mem = (mem > THRESH) ? 0.0f : base;
        }
        float spike = (mem > THRESH) ? 1.0f : 0.0f;

        // 10 output dots over this block's 64 h, 64-lane shfl reduction
        #pragma unroll
        for (int o = 0; o < NO; ++o) {
            float p = spike * ow[o * NH + hgrp * 64 + t];
            p += __shfl_down(p, 32);
            p += __shfl_down(p, 16);
            p += __shfl_down(p, 8);
            p += __shfl_down(p, 4);
            p += __shfl_down(p, 2);
            p += __shfl_down(p, 1);
            if (t == 0) partial[(b * 16 + hgrp) * NO + o] = p;
        }
    }
}

// ---------------- Kernel 3: micro softmax over summed partials ----------------
__global__ __launch_bounds__(64) void k_softmax(
    const float* __restrict__ partial,  // [B][16][10]
    const float* __restrict__ ob,       // [10]
    float* __restrict__ out)            // [B][10]
{
    int t = threadIdx.x;
    if (t < NB) {
        const float* p = partial + t * 16 * NO;
        float v[NO];
        #pragma unroll
        for (int o = 0; o < NO; ++o) v[o] = ob[o];
        #pragma unroll
        for (int hg = 0; hg < 16; ++hg)
            #pragma unroll
            for (int o = 0; o < NO; ++o) v[o] += p[hg * NO + o];

        float mx = -1e30f;
        #pragma unroll
        for (int o = 0; o < NO; ++o) mx = fmaxf(mx, v[o]);
        float sum = 0.0f;
        #pragma unroll
        for (int o = 0; o < NO; ++o) { v[o] = expf(v[o] - mx); sum += v[o]; }
        float inv = 1.0f / sum;
        #pragma unroll
        for (int o = 0; o < NO; ++o) out[t * NO + o] = v[o] * inv;
    }
}

extern "C" void kernel_launch(void* const* d_in, const int* in_sizes, int n_in,
                              void* d_out, int out_size, void* d_ws, size_t ws_size,
                              hipStream_t stream) {
    const f32x4*  x  = (const f32x4*)d_in[0];   // [32][2000][512][4]
    const float*  cw = (const float*)d_in[1];   // [4]
    const float*  cb = (const float*)d_in[2];   // [1]
    const float*  hw = (const float*)d_in[3];   // [1024][512]
    const float*  hb = (const float*)d_in[4];   // [1024]
    const float*  ow = (const float*)d_in[5];   // [10][1024]
    const float*  ob = (const float*)d_in[6];   // [10]
    float* out = (float*)d_out;                 // [32][10]

    char* ws = (char*)d_ws;
    float* spk1    = (float*)(ws);                        // 32*20*512*4 = 1,310,720 B
    float* wT      = (float*)(ws + 1310720);              // 512*1024*4  = 2,097,152 B
    float* partial = (float*)(ws + 1310720 + 2097152);    // 32*16*10*4  =    20,480 B

    // stage 1: conv + scan1 (~78us, HBM roofline) fused with weight transpose
    k1_conv_scan_tr<<<1792, 256, 0, stream>>>(x, cw, cb, spk1, hw, wT);

    // stage 2+3+4a: hidden GEMM (2 blocks/CU) + scan2 + output partial dots
    k2_hidden_scan<<<NB * 16, 256, 0, stream>>>(spk1, wT, hb, ow, partial);

    // stage 4b: sum partials + bias + softmax (1 tiny block)
    k_softmax<<<1, 64, 0, stream>>>(partial, ob, out);
}